// Round 1
// baseline (1080.224 us; speedup 1.0000x reference)
//
#include <hip/hip_runtime.h>

#define T_FRAMES 2048
#define D_DIM    1024
#define V_DIM    28

// ---------------------------------------------------------------------------
// Kernel A: context[d] = sum_t x[t][d]   (softmax over size-1 axis == 1, so
// the attention weights are all-ones and context is constant across steps)
// ---------------------------------------------------------------------------
__global__ __launch_bounds__(1024) void colsum_kernel(const float* __restrict__ x,
                                                      float* __restrict__ context) {
    int d  = threadIdx.x;            // 0..1023 == column
    int t0 = blockIdx.x * 128;       // 16 blocks * 128 rows = 2048
    float s = 0.f;
#pragma unroll 8
    for (int r = 0; r < 128; ++r)
        s += x[(size_t)(t0 + r) * D_DIM + d];
    atomicAdd(&context[d], s);       // 16-way contention per address, cheap
}

// ---------------------------------------------------------------------------
// Kernel B: c[i] = Co[i,:] . context     (28 dot products of length 1024)
// ---------------------------------------------------------------------------
__global__ __launch_bounds__(64) void cvec_kernel(const float* __restrict__ Co,
                                                  const float* __restrict__ context,
                                                  float* __restrict__ c) {
    int i    = blockIdx.x;           // 0..27
    int lane = threadIdx.x;          // one wave
    float s = 0.f;
#pragma unroll
    for (int m = 0; m < 16; ++m) {
        int k = lane + 64 * m;
        s += Co[(size_t)i * D_DIM + k] * context[k];
    }
#pragma unroll
    for (int off = 32; off > 0; off >>= 1) s += __shfl_down(s, off);
    if (lane == 0) c[i] = s;
}

// ---------------------------------------------------------------------------
// Kernel C: Bmat[t][i] = Uo[i,:] . x[t-1]   (row 0 = 0 : H init is zeros)
// One block per t; x-row staged in LDS; 4 waves x 7 rows each.
// ---------------------------------------------------------------------------
__global__ __launch_bounds__(256) void umat_kernel(const float* __restrict__ x,
                                                   const float* __restrict__ Uo,
                                                   float* __restrict__ Bmat) {
    int t   = blockIdx.x;
    int tid = threadIdx.x;
    if (t == 0) {                    // whole block exits together: barrier safe
        if (tid < V_DIM) Bmat[tid] = 0.f;
        return;
    }
    __shared__ float xs[D_DIM];
    const float* xrow = x + (size_t)(t - 1) * D_DIM;
#pragma unroll
    for (int m = 0; m < 4; ++m) xs[tid + 256 * m] = xrow[tid + 256 * m];
    __syncthreads();

    int wave = tid >> 6, lane = tid & 63;
#pragma unroll
    for (int r = 0; r < 7; ++r) {
        int i = wave * 7 + r;        // rows 0..27
        const float* urow = Uo + (size_t)i * D_DIM;
        float s = 0.f;
#pragma unroll
        for (int m = 0; m < 16; ++m) {
            int k = lane + 64 * m;   // coalesced Uo read, conflict-free LDS read
            s += urow[k] * xs[k];
        }
#pragma unroll
        for (int off = 32; off > 0; off >>= 1) s += __shfl_down(s, off);
        if (lane == 0) Bmat[(size_t)t * V_DIM + i] = s;
    }
}

// ---------------------------------------------------------------------------
// Kernel D: the sequential recurrence  y_t = sigmoid(Wo@y_{t-1} + Bmat[t] + c)
// Single wave; lane i owns output i; Wo row i in 28 VGPRs; broadcast of
// y_{t-1} via v_readlane (no LDS, no barrier); next Bmat row prefetched.
// ---------------------------------------------------------------------------
__global__ __launch_bounds__(64) void scan_kernel(const float* __restrict__ Bmat,
                                                  const float* __restrict__ c,
                                                  const float* __restrict__ Wo,
                                                  float* __restrict__ out) {
    int lane = threadIdx.x;
    bool act = lane < V_DIM;

    float w[V_DIM];
#pragma unroll
    for (int j = 0; j < V_DIM; ++j)
        w[j] = act ? Wo[(size_t)lane * V_DIM + j] : 0.f;
    float ci   = act ? c[lane] : 0.f;
    float y    = 0.f;                      // Y init = zeros (all lanes finite)
    float bcur = act ? Bmat[lane] : 0.f;   // row 0 (zeros)

    for (int t = 0; t < T_FRAMES; ++t) {
        // prefetch next row: off the dependency chain, hides ~200cyc latency
        float bnext = 0.f;
        if (t + 1 < T_FRAMES && act) bnext = Bmat[(size_t)(t + 1) * V_DIM + lane];

        float a0 = bcur + ci, a1 = 0.f, a2 = 0.f, a3 = 0.f;
        int yi = __float_as_int(y);
#pragma unroll
        for (int j = 0; j < V_DIM; j += 4) {   // 4 chains, 7 deep each
            a0 = fmaf(w[j + 0], __int_as_float(__builtin_amdgcn_readlane(yi, j + 0)), a0);
            a1 = fmaf(w[j + 1], __int_as_float(__builtin_amdgcn_readlane(yi, j + 1)), a1);
            a2 = fmaf(w[j + 2], __int_as_float(__builtin_amdgcn_readlane(yi, j + 2)), a2);
            a3 = fmaf(w[j + 3], __int_as_float(__builtin_amdgcn_readlane(yi, j + 3)), a3);
        }
        float acc = (a0 + a1) + (a2 + a3);
        float e = __expf(-acc);                       // v_exp_f32 path
        y = __builtin_amdgcn_rcpf(1.f + e);           // sigmoid, ~1ulp
        if (act) out[(size_t)t * V_DIM + lane] = y;   // fire-and-forget store
        bcur = bnext;
    }
}

// ---------------------------------------------------------------------------
extern "C" void kernel_launch(void* const* d_in, const int* in_sizes, int n_in,
                              void* d_out, int out_size, void* d_ws, size_t ws_size,
                              hipStream_t stream) {
    const float* x  = (const float*)d_in[0];
    // d_in[1]=Wa, d_in[2]=Ua, d_in[3]=Va: dead code (softmax over size-1 axis)
    const float* Wo = (const float*)d_in[4];
    const float* Uo = (const float*)d_in[5];
    const float* Co = (const float*)d_in[6];
    float* out = (float*)d_out;

    float* W       = (float*)d_ws;
    float* context = W;                 // 1024 floats
    float* c       = W + 1024;          // 28 floats
    float* Bmat    = W + 2048;          // 2048*28 floats (~229 KB)

    hipMemsetAsync(d_ws, 0, 1024 * sizeof(float), stream);  // zero context accs
    colsum_kernel<<<16,   1024, 0, stream>>>(x, context);
    cvec_kernel  <<<28,   64,   0, stream>>>(Co, context, c);
    umat_kernel  <<<2048, 256,  0, stream>>>(x, Uo, Bmat);
    scan_kernel  <<<1,    64,   0, stream>>>(Bmat, c, Wo, out);
}

// Round 2
// 500.389 us; speedup vs baseline: 2.1588x; 2.1588x over previous
//
#include <hip/hip_runtime.h>

#define T_FRAMES 2048
#define D_DIM    1024
#define V_DIM    28
#define BSTRIDE  32                 // Bmat row stride (padded, pow2)
#define WIN      16                 // steps per store/prefetch window
#define NWIN     (T_FRAMES / WIN)   // 128

// ---------------------------------------------------------------------------
// Kernel A: context[d] = sum_t x[t][d]   (softmax over size-1 axis == 1, so
// attention weights are all-ones and context is constant across steps)
// ---------------------------------------------------------------------------
__global__ __launch_bounds__(1024) void colsum_kernel(const float* __restrict__ x,
                                                      float* __restrict__ context) {
    int d  = threadIdx.x;
    int t0 = blockIdx.x * 128;       // 16 blocks * 128 rows = 2048
    float s = 0.f;
#pragma unroll 8
    for (int r = 0; r < 128; ++r)
        s += x[(size_t)(t0 + r) * D_DIM + d];
    atomicAdd(&context[d], s);
}

// ---------------------------------------------------------------------------
// Kernel B: c[i] = Co[i,:] . context
// ---------------------------------------------------------------------------
__global__ __launch_bounds__(64) void cvec_kernel(const float* __restrict__ Co,
                                                  const float* __restrict__ context,
                                                  float* __restrict__ c) {
    int i    = blockIdx.x;
    int lane = threadIdx.x;
    float s = 0.f;
#pragma unroll
    for (int m = 0; m < 16; ++m) {
        int k = lane + 64 * m;
        s += Co[(size_t)i * D_DIM + k] * context[k];
    }
#pragma unroll
    for (int off = 32; off > 0; off >>= 1) s += __shfl_down(s, off);
    if (lane == 0) c[i] = s;
}

// ---------------------------------------------------------------------------
// Kernel C: Bmat[t][i] = Uo[i,:] . x[t-1]  (row 0 = 0), stride-32 padded rows
// ---------------------------------------------------------------------------
__global__ __launch_bounds__(256) void umat_kernel(const float* __restrict__ x,
                                                   const float* __restrict__ Uo,
                                                   float* __restrict__ Bmat) {
    int t   = blockIdx.x;
    int tid = threadIdx.x;
    if (t == 0) {                    // whole block exits together: barrier safe
        if (tid < BSTRIDE) Bmat[tid] = 0.f;
        return;
    }
    if (tid < 4) Bmat[(size_t)t * BSTRIDE + V_DIM + tid] = 0.f;  // zero padding

    __shared__ float xs[D_DIM];
    const float* xrow = x + (size_t)(t - 1) * D_DIM;
#pragma unroll
    for (int m = 0; m < 4; ++m) xs[tid + 256 * m] = xrow[tid + 256 * m];
    __syncthreads();

    int wave = tid >> 6, lane = tid & 63;
#pragma unroll
    for (int r = 0; r < 7; ++r) {
        int i = wave * 7 + r;
        const float* urow = Uo + (size_t)i * D_DIM;
        float s = 0.f;
#pragma unroll
        for (int m = 0; m < 16; ++m) {
            int k = lane + 64 * m;
            s += urow[k] * xs[k];
        }
#pragma unroll
        for (int off = 32; off > 0; off >>= 1) s += __shfl_down(s, off);
        if (lane == 0) Bmat[(size_t)t * BSTRIDE + i] = s;
    }
}

// ---------------------------------------------------------------------------
// Kernel D: y_t = sigmoid(Wo@y_{t-1} + Bmat[t] + c), 2048 sequential steps.
// Single wave, lane i owns output i. Key perf structure:
//  - stores bursted every WIN steps (vmcnt is IN-ORDER across loads+stores:
//    interleaving a store per step made every load wait on a store-ack)
//  - Bmat prefetched a full window ahead via ping-pong register buffers
//  - log2e folded into weights: sigmoid = rcp(1 + exp2(-acc))
// ---------------------------------------------------------------------------
__global__ __launch_bounds__(64) void scan_kernel(const float* __restrict__ Bmat,
                                                  const float* __restrict__ c,
                                                  const float* __restrict__ Wo,
                                                  float* __restrict__ out) {
    const float LOG2E = 1.44269504088896f;
    int lane = threadIdx.x;
    bool act = lane < V_DIM;
    int bl   = lane & (BSTRIDE - 1);     // all 64 lanes load (28..31 = pad zeros)

    float w[V_DIM];
#pragma unroll
    for (int j = 0; j < V_DIM; ++j)
        w[j] = act ? Wo[(size_t)lane * V_DIM + j] * LOG2E : 0.f;
    float cik = act ? c[lane] * LOG2E : 0.f;

    float y = 0.f;
    float ybuf[WIN];
    float bA[WIN], bB[WIN];

    auto load_window = [&](float (&bX)[WIN], int wnd) {
        int ws = (wnd < NWIN) ? wnd : 0;           // keep addr in-bounds
#pragma unroll
        for (int s = 0; s < WIN; ++s)
            bX[s] = Bmat[(size_t)(ws * WIN + s) * BSTRIDE + bl];
    };

    auto do_window = [&](float (&bX)[WIN], int t0) {
#pragma unroll
        for (int s = 0; s < WIN; ++s) {
            int yi = __float_as_int(y);
            float a0 = fmaf(bX[s], LOG2E, cik);    // off-chain scale of b
            float a1 = 0.f, a2 = 0.f, a3 = 0.f;
#pragma unroll
            for (int j = 0; j < V_DIM; j += 4) {   // 4 chains, 7 deep
                a0 = fmaf(w[j + 0], __int_as_float(__builtin_amdgcn_readlane(yi, j + 0)), a0);
                a1 = fmaf(w[j + 1], __int_as_float(__builtin_amdgcn_readlane(yi, j + 1)), a1);
                a2 = fmaf(w[j + 2], __int_as_float(__builtin_amdgcn_readlane(yi, j + 2)), a2);
                a3 = fmaf(w[j + 3], __int_as_float(__builtin_amdgcn_readlane(yi, j + 3)), a3);
            }
            float acc = (a0 + a1) + (a2 + a3);
            float e = __builtin_amdgcn_exp2f(-acc);
            y = __builtin_amdgcn_rcpf(1.f + e);
            ybuf[s] = y;
        }
        if (act) {                                 // one exec-mask toggle per burst
#pragma unroll
            for (int s = 0; s < WIN; ++s)
                out[(size_t)(t0 + s) * V_DIM + lane] = ybuf[s];
        }
    };

    load_window(bA, 0);
    for (int wnd = 0; wnd < NWIN; wnd += 2) {
        load_window(bB, wnd + 1);
        do_window(bA, wnd * WIN);
        load_window(bA, wnd + 2);
        do_window(bB, (wnd + 1) * WIN);
    }
}

// ---------------------------------------------------------------------------
extern "C" void kernel_launch(void* const* d_in, const int* in_sizes, int n_in,
                              void* d_out, int out_size, void* d_ws, size_t ws_size,
                              hipStream_t stream) {
    const float* x  = (const float*)d_in[0];
    // d_in[1]=Wa, d_in[2]=Ua, d_in[3]=Va: dead code (softmax over size-1 axis)
    const float* Wo = (const float*)d_in[4];
    const float* Uo = (const float*)d_in[5];
    const float* Co = (const float*)d_in[6];
    float* out = (float*)d_out;

    float* W       = (float*)d_ws;
    float* context = W;                 // 1024 floats
    float* c       = W + 1024;          // 28 floats
    float* Bmat    = W + 2048;          // 2048*32 floats (256 KB)

    hipMemsetAsync(d_ws, 0, 1024 * sizeof(float), stream);
    colsum_kernel<<<16,   1024, 0, stream>>>(x, context);
    cvec_kernel  <<<28,   64,   0, stream>>>(Co, context, c);
    umat_kernel  <<<2048, 256,  0, stream>>>(x, Uo, Bmat);
    scan_kernel  <<<1,    64,   0, stream>>>(Bmat, c, Wo, out);
}